// Round 3
// baseline (667.999 us; speedup 1.0000x reference)
//
#include <hip/hip_runtime.h>
#include <math.h>

// Sizes (fixed by the problem)
#define BATCH 512   // scan sequence length (original batch dim)
#define E     128
#define DI    256
#define S     256
#define DTR   8
#define KCONV 4
#define JWX   520   // dt(8) + B(256) + C(256)
#define NC    32    // scan chunks (same as verified R1 path -> same numerics)
#define TCV   (BATCH / NC)
#define NBLK  512   // persistent grid: 2 blocks/CU x 256 CU

__device__ __forceinline__ float silu_f(float v) {
    return v / (1.0f + __expf(-v));
}

// ---------------------------------------------------------------------------
// Software grid barrier (device/agent scope; safe across XCDs).
// Requires all NBLK blocks resident -- guaranteed by __launch_bounds__(256,2)
// (VGPR<=128 -> >=2 blocks/CU; LDS ~12KB; 512 = 2 x 256 CUs).
// ---------------------------------------------------------------------------
__device__ __forceinline__ void gridbar(int* cnt, int* gen) {
    __syncthreads();
    if (threadIdx.x == 0) {
        __threadfence();   // drain this block's writes to device scope
        const int g = __hip_atomic_load(gen, __ATOMIC_RELAXED, __HIP_MEMORY_SCOPE_AGENT);
        const int arrived =
            __hip_atomic_fetch_add(cnt, 1, __ATOMIC_ACQ_REL, __HIP_MEMORY_SCOPE_AGENT) + 1;
        if (arrived == NBLK) {
            __hip_atomic_store(cnt, 0, __ATOMIC_RELAXED, __HIP_MEMORY_SCOPE_AGENT);
            __hip_atomic_store(gen, g + 1, __ATOMIC_RELEASE, __HIP_MEMORY_SCOPE_AGENT);
        } else {
            while (__hip_atomic_load(gen, __ATOMIC_ACQUIRE, __HIP_MEMORY_SCOPE_AGENT) == g)
                __builtin_amdgcn_s_sleep(4);
        }
        __threadfence();   // invalidate stale lines before consuming others' data
    }
    __syncthreads();
}

__global__ void kinit(int* cnt, int* gen) {
    if (threadIdx.x == 0) { *cnt = 0; *gen = 0; }
}

// ===========================================================================
// MEGA persistent kernel: whole forward pass, 4 software barriers instead of
// 4 kernel boundaries. Launched with a plain (capturable) dispatch.
// ===========================================================================
__global__ __launch_bounds__(256, 2) void mega(
    const float* __restrict__ x, const float* __restrict__ conv_w,
    const float* __restrict__ conv_b, const float* __restrict__ lin_w,
    const float* __restrict__ lin_b, const float* __restrict__ W_in,
    const float* __restrict__ c1w, const float* __restrict__ conv1d_b,
    const float* __restrict__ W_x, const float* __restrict__ W_dt,
    const float* __restrict__ b_dt, const float* __restrict__ A_log,
    const float* __restrict__ Dp, const float* __restrict__ W_out,
    const float* __restrict__ We, const float* __restrict__ be,
    const float* __restrict__ Wa, const float* __restrict__ ba,
    const float* __restrict__ Wq, const float* __restrict__ bq,
    float* __restrict__ out,
    float* __restrict__ xm, float* __restrict__ zg,
    float* __restrict__ xs_g, float* __restrict__ delta_g,
    float* __restrict__ Bm, float* __restrict__ Cm,
    float* __restrict__ y,
    float* __restrict__ W_xT, float* __restrict__ W_outT,
    float* __restrict__ hloc, float* __restrict__ Dchunk,
    int* __restrict__ bcnt, int* __restrict__ bgen)
{
    const int tid  = threadIdx.x;
    const int bid  = blockIdx.x;
    const int wv = tid >> 6, ln = tid & 63;

    __shared__ float lw[1024];
    __shared__ float red[10][4];
    __shared__ float Tsh[10];
    __shared__ float ush[E];
    __shared__ float xs_sh[4][DI];
    __shared__ float dtin[4][8];
    __shared__ float yf[2][DI];
    __shared__ float feat[2][E];

    // ---------------- Phase 0: conv2d+lin row31 -> u -> W_in proj; transposes
    for (int v = bid; v < 523; v += NBLK) {
        if (v >= 512) {
            const int t = v - 512;
            const float* src; float* dst; int J, K, j0;
            if (t < 9) { src = W_x;   dst = W_xT;   J = JWX; K = DI; j0 = t * 64; }
            else       { src = W_out; dst = W_outT; J = E;   K = DI; j0 = (t - 9) * 64; }
            const int j = j0 + ln;
            if (j < J) {
                for (int c = wv; c < K; c += 4)
                    dst[c * J + j] = src[j * K + c];
            }
        } else {
            const int b = v;
            const float4 lv = ((const float4*)(lin_w + 31 * 1024))[tid];
            ((float4*)lw)[tid] = lv;
            __syncthreads();

            float acc[10];
#pragma unroll
            for (int k = 0; k < 10; k++) acc[k] = 0.0f;

            const float4 xv = ((const float4*)(x + (size_t)b * 1024))[tid];
            const int p0 = tid * 4;
            const int h = p0 >> 5, w0 = p0 & 31;
            const float xa[4] = {xv.x, xv.y, xv.z, xv.w};
#pragma unroll
            for (int k = 0; k < 4; k++) {
                const float xval = xa[k];
                const int w = w0 + k;
#pragma unroll
                for (int i = 0; i < 3; i++) {
                    const int hh = h - (i - 1);
                    if (hh < 0 || hh > 31) continue;
#pragma unroll
                    for (int j = 0; j < 3; j++) {
                        const int ww = w - (j - 1);
                        if (ww < 0 || ww > 31) continue;
                        acc[i * 3 + j] += xval * lw[hh * 32 + ww];
                    }
                }
            }
            acc[9] = lv.x + lv.y + lv.z + lv.w;   // partial sum of lin_w row

#pragma unroll
            for (int k = 0; k < 10; k++) {
#pragma unroll
                for (int m = 1; m < 64; m <<= 1) acc[k] += __shfl_xor(acc[k], m, 64);
            }
            if (ln == 0) {
#pragma unroll
                for (int k = 0; k < 10; k++) red[k][wv] = acc[k];
            }
            __syncthreads();
            if (tid < 10) Tsh[tid] = red[tid][0] + red[tid][1] + red[tid][2] + red[tid][3];
            __syncthreads();

            if (tid < E) {
                const int e = tid;
                float val = lin_b[31] + conv_b[e] * Tsh[9];
#pragma unroll
                for (int k = 0; k < 9; k++) val += conv_w[e * 9 + k] * Tsh[k];
                ush[e] = val;
            }
            __syncthreads();

            // fused W_in projection: j=tid -> xm, j=tid+256 -> zg
            {
                const float4* w0p = (const float4*)(W_in + (size_t)tid * E);
                const float4* w1p = (const float4*)(W_in + (size_t)(tid + 256) * E);
                float a0 = 0.0f;
#pragma unroll 8
                for (int e4 = 0; e4 < E / 4; e4++) {
                    const float4 w = w0p[e4];
                    a0 += ush[4*e4]*w.x + ush[4*e4+1]*w.y + ush[4*e4+2]*w.z + ush[4*e4+3]*w.w;
                }
                float a1 = 0.0f;
#pragma unroll 8
                for (int e4 = 0; e4 < E / 4; e4++) {
                    const float4 w = w1p[e4];
                    a1 += ush[4*e4]*w.x + ush[4*e4+1]*w.y + ush[4*e4+2]*w.z + ush[4*e4+3]*w.w;
                }
                xm[b * DI + tid] = a0;
                zg[b * DI + tid] = a1;
            }
            __syncthreads();
        }
    }

    gridbar(bcnt, bgen);

    // ---------------- Phase 1: conv1d+silu (local recompute) + W_x proj + delta
    for (int v = bid; v < 128 * 9; v += NBLK) {
        const int g  = v >> 7;
        const int bb = (v & 127) * 4;

        for (int idx = tid; idx < 4 * DI; idx += 256) {
            const int r = idx >> 8, c = idx & 255;
            const int b = bb + r;
            const float4 wc = ((const float4*)c1w)[c];   // taps k=0..3
            float a = conv1d_b[c];
            if (b >= 3) a += xm[(b - 3) * DI + c] * wc.x;
            if (b >= 2) a += xm[(b - 2) * DI + c] * wc.y;
            if (b >= 1) a += xm[(b - 1) * DI + c] * wc.z;
            a += xm[b * DI + c] * wc.w;
            const float s = silu_f(a);
            xs_sh[r][c] = s;
            if (g == 0) xs_g[b * DI + c] = s;
        }
        __syncthreads();

        const int r = tid >> 6;
        const int j = g * 64 + ln;
        if (j < JWX) {
            float a = 0.0f;
#pragma unroll 8
            for (int c = 0; c < DI; c++) a += xs_sh[r][c] * W_xT[c * JWX + j];
            const int b = bb + r;
            if (j < DTR)          dtin[r][j] = a;
            else if (j < DTR + S) Bm[b * S + (j - DTR)] = a;
            else                  Cm[b * S + (j - DTR - S)] = a;
        }
        __syncthreads();

        if (g == 0) {
            const int d = tid;
            const float bd = b_dt[d];
            const float4 wd0 = ((const float4*)(W_dt + d * DTR))[0];
            const float4 wd1 = ((const float4*)(W_dt + d * DTR))[1];
#pragma unroll
            for (int r2 = 0; r2 < 4; r2++) {
                float a = bd
                    + dtin[r2][0]*wd0.x + dtin[r2][1]*wd0.y + dtin[r2][2]*wd0.z + dtin[r2][3]*wd0.w
                    + dtin[r2][4]*wd1.x + dtin[r2][5]*wd1.y + dtin[r2][6]*wd1.z + dtin[r2][7]*wd1.w;
                delta_g[(bb + r2) * DI + d] = (a > 20.0f) ? a : log1pf(__expf(a));
            }
        }
        __syncthreads();
    }

    gridbar(bcnt, bgen);

    // ---------------- Phase 2: up-sweep (hloc, Dchunk)
    for (int v = bid; v < 64 * NC; v += NBLK) {
        const int xp = v & 63, c = v >> 6;
        const int d = xp * 4 + wv;
        const int s0 = ln * 4;
        const int t0 = c * TCV;

        const float4 al = *(const float4*)(A_log + d * S + s0);
        float4 A;
        A.x = -__expf(al.x); A.y = -__expf(al.y);
        A.z = -__expf(al.z); A.w = -__expf(al.w);

        float4 h = make_float4(0.f, 0.f, 0.f, 0.f);
        float cd = 0.0f;
        for (int tb = 0; tb < TCV; tb += 8) {
#pragma unroll
            for (int i = 0; i < 8; i++) {
                const int tt = t0 + tb + i;
                const float dd = delta_g[tt * DI + d];
                cd += dd;
                const float u = dd * xs_g[tt * DI + d];
                const float4 B = *(const float4*)(Bm + tt * S + s0);
                h.x = __expf(dd * A.x) * h.x + u * B.x;
                h.y = __expf(dd * A.y) * h.y + u * B.y;
                h.z = __expf(dd * A.z) * h.z + u * B.z;
                h.w = __expf(dd * A.w) * h.w + u * B.w;
            }
        }
        *(float4*)(hloc + ((size_t)(c * DI + d)) * S + s0) = h;
        if (ln == 0) Dchunk[c * DI + d] = cd;
    }

    gridbar(bcnt, bgen);

    // ---------------- Phase 3: down-sweep (carry Horner + recurrence -> y)
    for (int v = bid; v < 64 * NC; v += NBLK) {
        const int xp = v & 63;
        const int c = (NC - 1) - (v >> 6);   // heavy carries first
        const int d = xp * 4 + wv;
        const int s0 = ln * 4;
        const int t0 = c * TCV;

        const float4 al = *(const float4*)(A_log + d * S + s0);
        float4 A;
        A.x = -__expf(al.x); A.y = -__expf(al.y);
        A.z = -__expf(al.z); A.w = -__expf(al.w);

        float4 h = make_float4(0.f, 0.f, 0.f, 0.f);
        for (int cp = 1; cp <= c; cp++) {
            const float4 hl = *(const float4*)(hloc + ((size_t)((cp - 1) * DI + d)) * S + s0);
            const float Dc = Dchunk[(cp - 1) * DI + d];
            h.x = hl.x + __expf(A.x * Dc) * h.x;
            h.y = hl.y + __expf(A.y * Dc) * h.y;
            h.z = hl.z + __expf(A.z * Dc) * h.z;
            h.w = hl.w + __expf(A.w * Dc) * h.w;
        }

        float pr[8];
        for (int tb = 0; tb < TCV; tb += 8) {
#pragma unroll
            for (int i = 0; i < 8; i++) {
                const int tt = t0 + tb + i;
                const float dd = delta_g[tt * DI + d];
                const float u = dd * xs_g[tt * DI + d];
                const float4 B = *(const float4*)(Bm + tt * S + s0);
                const float4 C = *(const float4*)(Cm + tt * S + s0);
                h.x = __expf(dd * A.x) * h.x + u * B.x;
                h.y = __expf(dd * A.y) * h.y + u * B.y;
                h.z = __expf(dd * A.z) * h.z + u * B.z;
                h.w = __expf(dd * A.w) * h.w + u * B.w;
                pr[i] = h.x * C.x + h.y * C.y + h.z * C.z + h.w * C.w;
            }
#pragma unroll
            for (int i = 0; i < 8; i++) {
#pragma unroll
                for (int m = 1; m < 64; m <<= 1) pr[i] += __shfl_xor(pr[i], m, 64);
            }
            if (ln == 0) {
#pragma unroll
                for (int i = 0; i < 8; i++) y[(t0 + tb + i) * DI + d] = pr[i];
            }
        }
    }

    gridbar(bcnt, bgen);

    // ---------------- Phase 4: heads
    for (int v = bid; v < 256; v += NBLK) {
        const int bb = v * 2;
        for (int idx = tid; idx < 2 * DI; idx += 256) {
            const int r = idx >> 8, cc = idx & 255;
            const int b = bb + r;
            const float z = zg[b * DI + cc];
            yf[r][cc] = (y[b * DI + cc] + xs_g[b * DI + cc] * Dp[cc]) * silu_f(z);
        }
        __syncthreads();
        {
            const int r = tid >> 7, e = tid & 127;
            float a = 0.0f;
#pragma unroll 8
            for (int dd = 0; dd < DI; dd++) a += yf[r][dd] * W_outT[dd * E + e];
            feat[r][e] = a;
        }
        __syncthreads();
        if (tid < 16) {
            const int r = tid >> 3, hd = tid & 7;
            const int b = bb + r;
            const float* wrow;
            float bias;
            int dst;
            if (hd == 0)      { wrow = We;                 bias = be[0];      dst = b; }
            else if (hd < 4)  { wrow = Wa + (hd - 1) * E;  bias = ba[hd - 1]; dst = 512 + b * 3 + (hd - 1); }
            else              { wrow = Wq + (hd - 4) * E;  bias = bq[hd - 4]; dst = 2048 + b * 4 + (hd - 4); }
            float a = bias;
#pragma unroll 4
            for (int e = 0; e < E; e++) a += feat[r][e] * wrow[e];
            out[dst] = a;
        }
        __syncthreads();
    }
}

// ===========================================================================
// Fallback path (workspace too small only): verified R1 multi-kernel chain.
// ===========================================================================
__global__ __launch_bounds__(256) void kA_pre(
    const float* __restrict__ x, const float* __restrict__ conv_w,
    const float* __restrict__ conv_b, const float* __restrict__ lin_w,
    const float* __restrict__ lin_b, const float* __restrict__ W_in,
    const float* __restrict__ W_x, const float* __restrict__ W_out,
    float* __restrict__ xm, float* __restrict__ zg,
    float* __restrict__ W_xT, float* __restrict__ W_outT)
{
    const int tid = threadIdx.x;
    if (blockIdx.x >= 512) {
        const int bid = blockIdx.x - 512;
        const float* src; float* dst; int J, K, j0;
        if (bid < 9) { src = W_x;   dst = W_xT;   J = JWX; K = DI; j0 = bid * 64; }
        else         { src = W_out; dst = W_outT; J = E;   K = DI; j0 = (bid - 9) * 64; }
        const int j = j0 + (tid & 63);
        if (j >= J) return;
        for (int c = tid >> 6; c < K; c += 4)
            dst[c * J + j] = src[j * K + c];
        return;
    }

    const int b = blockIdx.x;
    __shared__ float lw[1024];
    __shared__ float red[10][4];
    __shared__ float Tsh[10];
    __shared__ float u[E];

    const float4 lv = ((const float4*)(lin_w + 31 * 1024))[tid];
    ((float4*)lw)[tid] = lv;
    __syncthreads();

    float acc[10];
#pragma unroll
    for (int k = 0; k < 10; k++) acc[k] = 0.0f;

    const float4 xv = ((const float4*)(x + (size_t)b * 1024))[tid];
    const int p0 = tid * 4;
    const int h = p0 >> 5, w0 = p0 & 31;
    const float xa[4] = {xv.x, xv.y, xv.z, xv.w};
#pragma unroll
    for (int k = 0; k < 4; k++) {
        const float xval = xa[k];
        const int w = w0 + k;
#pragma unroll
        for (int i = 0; i < 3; i++) {
            const int hh = h - (i - 1);
            if (hh < 0 || hh > 31) continue;
#pragma unroll
            for (int j = 0; j < 3; j++) {
                const int ww = w - (j - 1);
                if (ww < 0 || ww > 31) continue;
                acc[i * 3 + j] += xval * lw[hh * 32 + ww];
            }
        }
    }
    acc[9] = lv.x + lv.y + lv.z + lv.w;

    const int wv = tid >> 6, ln = tid & 63;
#pragma unroll
    for (int k = 0; k < 10; k++) {
#pragma unroll
        for (int m = 1; m < 64; m <<= 1) acc[k] += __shfl_xor(acc[k], m, 64);
    }
    if (ln == 0) {
#pragma unroll
        for (int k = 0; k < 10; k++) red[k][wv] = acc[k];
    }
    __syncthreads();
    if (tid < 10) Tsh[tid] = red[tid][0] + red[tid][1] + red[tid][2] + red[tid][3];
    __syncthreads();

    if (tid < E) {
        const int e = tid;
        float v = lin_b[31] + conv_b[e] * Tsh[9];
#pragma unroll
        for (int k = 0; k < 9; k++) v += conv_w[e * 9 + k] * Tsh[k];
        u[e] = v;
    }
    __syncthreads();

    {
        const float4* w0p = (const float4*)(W_in + (size_t)tid * E);
        const float4* w1p = (const float4*)(W_in + (size_t)(tid + 256) * E);
        float a0 = 0.0f;
#pragma unroll 8
        for (int e4 = 0; e4 < E / 4; e4++) {
            const float4 w = w0p[e4];
            a0 += u[4*e4]*w.x + u[4*e4+1]*w.y + u[4*e4+2]*w.z + u[4*e4+3]*w.w;
        }
        float a1 = 0.0f;
#pragma unroll 8
        for (int e4 = 0; e4 < E / 4; e4++) {
            const float4 w = w1p[e4];
            a1 += u[4*e4]*w.x + u[4*e4+1]*w.y + u[4*e4+2]*w.z + u[4*e4+3]*w.w;
        }
        xm[b * DI + tid] = a0;
        zg[b * DI + tid] = a1;
    }
}

__global__ __launch_bounds__(256) void k2b_conv_wx(
    const float* __restrict__ xm, const float* __restrict__ c1w,
    const float* __restrict__ conv1d_b, const float* __restrict__ W_xT,
    const float* __restrict__ W_dt, const float* __restrict__ b_dt,
    float* __restrict__ xs_g, float* __restrict__ delta_g,
    float* __restrict__ Bm, float* __restrict__ Cm)
{
    const int bb = blockIdx.x * 4;
    const int g = blockIdx.y;
    const int tid = threadIdx.x;
    __shared__ float xs[4][DI];
    __shared__ float dtin[4][8];

    for (int idx = tid; idx < 4 * DI; idx += 256) {
        const int r = idx >> 8, c = idx & 255;
        const int b = bb + r;
        const float4 wc = ((const float4*)c1w)[c];
        float a = conv1d_b[c];
        if (b >= 3) a += xm[(b - 3) * DI + c] * wc.x;
        if (b >= 2) a += xm[(b - 2) * DI + c] * wc.y;
        if (b >= 1) a += xm[(b - 1) * DI + c] * wc.z;
        a += xm[b * DI + c] * wc.w;
        const float s = silu_f(a);
        xs[r][c] = s;
        if (g == 0) xs_g[b * DI + c] = s;
    }
    __syncthreads();

    const int r = tid >> 6;
    const int j = g * 64 + (tid & 63);
    if (j < JWX) {
        float a = 0.0f;
#pragma unroll 8
        for (int c = 0; c < DI; c++) a += xs[r][c] * W_xT[c * JWX + j];
        const int b = bb + r;
        if (j < DTR)          dtin[r][j] = a;
        else if (j < DTR + S) Bm[b * S + (j - DTR)] = a;
        else                  Cm[b * S + (j - DTR - S)] = a;
    }
    __syncthreads();

    if (g == 0) {
        const int d = tid;
        const float bd = b_dt[d];
        const float4 wd0 = ((const float4*)(W_dt + d * DTR))[0];
        const float4 wd1 = ((const float4*)(W_dt + d * DTR))[1];
#pragma unroll
        for (int r2 = 0; r2 < 4; r2++) {
            float a = bd
                + dtin[r2][0]*wd0.x + dtin[r2][1]*wd0.y + dtin[r2][2]*wd0.z + dtin[r2][3]*wd0.w
                + dtin[r2][4]*wd1.x + dtin[r2][5]*wd1.y + dtin[r2][6]*wd1.z + dtin[r2][7]*wd1.w;
            const float sp = (a > 20.0f) ? a : log1pf(__expf(a));
            delta_g[(bb + r2) * DI + d] = sp;
        }
    }
}

__global__ __launch_bounds__(256) void k3u_up(
    const float* __restrict__ A_log, const float* __restrict__ delta,
    const float* __restrict__ xs, const float* __restrict__ Bm,
    float* __restrict__ hloc, float* __restrict__ Dchunk)
{
    const int tid = threadIdx.x;
    const int wv = tid >> 6, ln = tid & 63;
    const int d = blockIdx.x * 4 + wv;
    const int c = blockIdx.y;
    const int s0 = ln * 4;
    const int t0 = c * TCV;

    const float4 al = *(const float4*)(A_log + d * S + s0);
    float4 A;
    A.x = -__expf(al.x); A.y = -__expf(al.y);
    A.z = -__expf(al.z); A.w = -__expf(al.w);

    float4 h = make_float4(0.f, 0.f, 0.f, 0.f);
    float cd = 0.0f;
    for (int tb = 0; tb < TCV; tb += 8) {
#pragma unroll
        for (int i = 0; i < 8; i++) {
            const int tt = t0 + tb + i;
            const float dd = delta[tt * DI + d];
            cd += dd;
            const float u = dd * xs[tt * DI + d];
            const float4 B = *(const float4*)(Bm + tt * S + s0);
            h.x = __expf(dd * A.x) * h.x + u * B.x;
            h.y = __expf(dd * A.y) * h.y + u * B.y;
            h.z = __expf(dd * A.z) * h.z + u * B.z;
            h.w = __expf(dd * A.w) * h.w + u * B.w;
        }
    }
    *(float4*)(hloc + ((size_t)(c * DI + d)) * S + s0) = h;
    if (ln == 0) Dchunk[c * DI + d] = cd;
}

__global__ __launch_bounds__(256) void k3d_down(
    const float* __restrict__ A_log, const float* __restrict__ delta,
    const float* __restrict__ xs, const float* __restrict__ Bm,
    const float* __restrict__ Cm, const float* __restrict__ hloc,
    const float* __restrict__ Dchunk, float* __restrict__ y)
{
    const int tid = threadIdx.x;
    const int wv = tid >> 6, ln = tid & 63;
    const int d = blockIdx.x * 4 + wv;
    const int c = (NC - 1) - blockIdx.y;
    const int s0 = ln * 4;
    const int t0 = c * TCV;

    const float4 al = *(const float4*)(A_log + d * S + s0);
    float4 A;
    A.x = -__expf(al.x); A.y = -__expf(al.y);
    A.z = -__expf(al.z); A.w = -__expf(al.w);

    float4 h = make_float4(0.f, 0.f, 0.f, 0.f);
    for (int cp = 1; cp <= c; cp++) {
        const float4 hl = *(const float4*)(hloc + ((size_t)((cp - 1) * DI + d)) * S + s0);
        const float Dc = Dchunk[(cp - 1) * DI + d];
        h.x = hl.x + __expf(A.x * Dc) * h.x;
        h.y = hl.y + __expf(A.y * Dc) * h.y;
        h.z = hl.z + __expf(A.z * Dc) * h.z;
        h.w = hl.w + __expf(A.w * Dc) * h.w;
    }

    float pr[8];
    for (int tb = 0; tb < TCV; tb += 8) {
#pragma unroll
        for (int i = 0; i < 8; i++) {
            const int tt = t0 + tb + i;
            const float dd = delta[tt * DI + d];
            const float u = dd * xs[tt * DI + d];
            const float4 B = *(const float4*)(Bm + tt * S + s0);
            const float4 C = *(const float4*)(Cm + tt * S + s0);
            h.x = __expf(dd * A.x) * h.x + u * B.x;
            h.y = __expf(dd * A.y) * h.y + u * B.y;
            h.z = __expf(dd * A.z) * h.z + u * B.z;
            h.w = __expf(dd * A.w) * h.w + u * B.w;
            pr[i] = h.x * C.x + h.y * C.y + h.z * C.z + h.w * C.w;
        }
#pragma unroll
        for (int i = 0; i < 8; i++) {
#pragma unroll
            for (int m = 1; m < 64; m <<= 1) pr[i] += __shfl_xor(pr[i], m, 64);
        }
        if (ln == 0) {
#pragma unroll
            for (int i = 0; i < 8; i++) y[(t0 + tb + i) * DI + d] = pr[i];
        }
    }
}

__global__ __launch_bounds__(256) void k4_heads(
    const float* __restrict__ y, const float* __restrict__ xs,
    const float* __restrict__ Dp, const float* __restrict__ zg,
    const float* __restrict__ W_outT,
    const float* __restrict__ We, const float* __restrict__ be,
    const float* __restrict__ Wa, const float* __restrict__ ba,
    const float* __restrict__ Wq, const float* __restrict__ bq,
    float* __restrict__ out)
{
    const int bb = blockIdx.x * 2;
    const int tid = threadIdx.x;
    __shared__ float yf[2][DI];
    __shared__ float feat[2][E];

    for (int idx = tid; idx < 2 * DI; idx += 256) {
        const int r = idx >> 8, c = idx & 255;
        const int b = bb + r;
        const float z = zg[b * DI + c];
        yf[r][c] = (y[b * DI + c] + xs[b * DI + c] * Dp[c]) * silu_f(z);
    }
    __syncthreads();

    {
        const int r = tid >> 7, e = tid & 127;
        float a = 0.0f;
#pragma unroll 8
        for (int dd = 0; dd < DI; dd++) a += yf[r][dd] * W_outT[dd * E + e];
        feat[r][e] = a;
    }
    __syncthreads();

    if (tid < 16) {
        const int r = tid >> 3, hd = tid & 7;
        const int b = bb + r;
        const float* wrow;
        float bias;
        int dst;
        if (hd == 0)      { wrow = We;                 bias = be[0];      dst = b; }
        else if (hd < 4)  { wrow = Wa + (hd - 1) * E;  bias = ba[hd - 1]; dst = 512 + b * 3 + (hd - 1); }
        else              { wrow = Wq + (hd - 4) * E;  bias = bq[hd - 4]; dst = 2048 + b * 4 + (hd - 4); }
        float a = bias;
#pragma unroll 4
        for (int e = 0; e < E; e++) a += feat[r][e] * wrow[e];
        out[dst] = a;
    }
}

// ===========================================================================
extern "C" void kernel_launch(void* const* d_in, const int* in_sizes, int n_in,
                              void* d_out, int out_size, void* d_ws, size_t ws_size,
                              hipStream_t stream)
{
    const float* x        = (const float*)d_in[0];
    const float* conv_w   = (const float*)d_in[1];
    const float* conv_b   = (const float*)d_in[2];
    const float* lin_w    = (const float*)d_in[3];
    const float* lin_b    = (const float*)d_in[4];
    const float* W_in     = (const float*)d_in[5];
    const float* conv1d_w = (const float*)d_in[6];
    const float* conv1d_b = (const float*)d_in[7];
    const float* W_x      = (const float*)d_in[8];
    const float* W_dt     = (const float*)d_in[9];
    const float* b_dt     = (const float*)d_in[10];
    const float* A_log    = (const float*)d_in[11];
    const float* Dp       = (const float*)d_in[12];
    const float* W_out    = (const float*)d_in[13];
    const float* We       = (const float*)d_in[14];
    const float* be       = (const float*)d_in[15];
    const float* Wa       = (const float*)d_in[16];
    const float* ba       = (const float*)d_in[17];
    const float* Wq       = (const float*)d_in[18];
    const float* bq       = (const float*)d_in[19];
    float* out = (float*)d_out;

    float* ws = (float*)d_ws;
    float* xm     = ws;                    // 512*256 each below
    float* zg     = xm     + 512 * 256;
    float* xs     = zg     + 512 * 256;
    float* delta  = xs     + 512 * 256;
    float* Bm     = delta  + 512 * 256;
    float* Cm     = Bm     + 512 * 256;
    float* y      = Cm     + 512 * 256;
    float* W_xT   = y      + 512 * 256;    // 256*520
    float* W_outT = W_xT   + 256 * JWX;    // 256*128
    float* hloc   = W_outT + 256 * 128;    // NC*DI*S
    float* Dchunk = hloc   + (size_t)NC * DI * S;   // NC*DI
    int*   bstate = (int*)(Dchunk + NC * DI);       // cnt, gen

    const size_t need_floats = (size_t)(Dchunk + NC * DI + 16 - ws);
    if (ws_size / 4 >= need_floats) {
        int* bcnt = bstate;
        int* bgen = bstate + 1;
        kinit<<<1, 64, 0, stream>>>(bcnt, bgen);
        mega<<<NBLK, 256, 0, stream>>>(
            x, conv_w, conv_b, lin_w, lin_b, W_in,
            conv1d_w, conv1d_b, W_x, W_dt, b_dt, A_log, Dp, W_out,
            We, be, Wa, ba, Wq, bq, out,
            xm, zg, xs, delta, Bm, Cm, y, W_xT, W_outT, hloc, Dchunk,
            bcnt, bgen);
    } else {
        kA_pre<<<523, 256, 0, stream>>>(x, conv_w, conv_b, lin_w, lin_b,
                                        W_in, W_x, W_out, xm, zg, W_xT, W_outT);
        k2b_conv_wx<<<dim3(128, 9), 256, 0, stream>>>(xm, conv1d_w, conv1d_b, W_xT,
                                                      W_dt, b_dt, xs, delta, Bm, Cm);
        k3u_up<<<dim3(64, NC), 256, 0, stream>>>(A_log, delta, xs, Bm, hloc, Dchunk);
        k3d_down<<<dim3(64, NC), 256, 0, stream>>>(A_log, delta, xs, Bm, Cm,
                                                   hloc, Dchunk, y);
        k4_heads<<<256, 256, 0, stream>>>(y, xs, Dp, zg, W_outT, We, be, Wa, ba, Wq, bq, out);
    }
}

// Round 4
// 366.098 us; speedup vs baseline: 1.8246x; 1.8246x over previous
//
#include <hip/hip_runtime.h>
#include <math.h>

// Sizes (fixed by the problem)
#define BATCH 512   // scan sequence length (original batch dim)
#define E     128
#define DI    256
#define S     256
#define DTR   8
#define KCONV 4
#define JWX   520   // dt(8) + B(256) + C(256)
#define NC    32    // scan chunks (same as verified R1 path -> same numerics)
#define TCV   (BATCH / NC)
#define NBLK  512   // persistent grid: 2 blocks/CU x 256 CU (residency proven R3)
#define SENT  0x7C3A91E5   // "task done" sentinel; != any plausible poison fill

__device__ __forceinline__ float silu_f(float v) {
    return v / (1.0f + __expf(-v));
}

__device__ __forceinline__ int ld_flag(const int* p) {
    return __hip_atomic_load(p, __ATOMIC_RELAXED, __HIP_MEMORY_SCOPE_AGENT);
}
__device__ __forceinline__ void st_flag(int* p, int v) {
    __hip_atomic_store(p, v, __ATOMIC_RELAXED, __HIP_MEMORY_SCOPE_AGENT);
}
__device__ __forceinline__ void acq_fence() {
    __builtin_amdgcn_fence(__ATOMIC_ACQUIRE, "agent");   // one L2 invalidate
}

__device__ __forceinline__ float dot128(const float* __restrict__ w,
                                        const float* __restrict__ u) {
    const float4* wp = (const float4*)w;
    float a = 0.0f;
#pragma unroll 8
    for (int e4 = 0; e4 < 32; e4++) {
        const float4 ww = wp[e4];
        a += u[4*e4]*ww.x + u[4*e4+1]*ww.y + u[4*e4+2]*ww.z + u[4*e4+3]*ww.w;
    }
    return a;
}

// ===========================================================================
// MEGA persistent kernel, data-flow flag synchronized (no global barriers).
//   blocks 0..127 : P01 (conv2d+lin -> u -> W_in -> conv1d -> W_x -> delta)
//                   for batch group g=bid (4 rows + 3 recomputed xm rows)
//   all blocks    : UP  tasks (xp=bid&63, c = bid>>6 + {0,8,16,24})
//                   DOWN tasks (same columns, ascending c)
//   blocks 256..511: HEADS for batch pair v=bid-256
// Flags: rowflag[g] (P01 done), upflag[c*64+xp] (hloc ready), donecnt[c]
// (64 DOWN arrivals). Producers: syncthreads (drains vmem) -> tid0
// threadfence (L2 writeback) -> relaxed sentinel store. Consumers: tid0
// relaxed poll -> single acquire fence -> syncthreads.
// ===========================================================================
__global__ __launch_bounds__(256, 2) void mega(
    const float* __restrict__ x, const float* __restrict__ conv_w,
    const float* __restrict__ conv_b, const float* __restrict__ lin_w,
    const float* __restrict__ lin_b, const float* __restrict__ W_in,
    const float* __restrict__ c1w, const float* __restrict__ conv1d_b,
    const float* __restrict__ W_x, const float* __restrict__ W_dt,
    const float* __restrict__ b_dt, const float* __restrict__ A_log,
    const float* __restrict__ Dp, const float* __restrict__ W_out,
    const float* __restrict__ We, const float* __restrict__ be,
    const float* __restrict__ Wa, const float* __restrict__ ba,
    const float* __restrict__ Wq, const float* __restrict__ bq,
    float* __restrict__ out,
    float* __restrict__ zg, float* __restrict__ xs_g,
    float* __restrict__ delta_g, float* __restrict__ Bm,
    float* __restrict__ Cm, float* __restrict__ y,
    float* __restrict__ hloc, float* __restrict__ Dchunk,
    int* __restrict__ rowflag, int* __restrict__ upflag,
    int* __restrict__ donecnt)
{
    const int tid = threadIdx.x;
    const int bid = blockIdx.x;
    const int wv = tid >> 6, ln = tid & 63;

    __shared__ float lw[1024];
    __shared__ float red[10][4];
    __shared__ float Tsh[10];
    __shared__ float ush[E];
    __shared__ float xml[7][DI];
    __shared__ float xs_sh[4][DI];
    __shared__ float dtin[4][8];
    __shared__ float yf[2][DI];
    __shared__ float feat[2][E];

    // ---------------- P01: batch group g = bid (bid < 128) -------------------
    if (bid < 128) {
        const int g = bid, bb = g * 4;

        const float4 lv = ((const float4*)(lin_w + 31 * 1024))[tid];
        ((float4*)lw)[tid] = lv;
        __syncthreads();

        for (int i = 0; i < 7; i++) {          // rows bb-3 .. bb+3
            const int b = bb - 3 + i;
            if (b < 0) continue;               // block-uniform

            float acc[10];
#pragma unroll
            for (int k = 0; k < 10; k++) acc[k] = 0.0f;

            const float4 xv = ((const float4*)(x + (size_t)b * 1024))[tid];
            const int p0 = tid * 4;
            const int h = p0 >> 5, w0 = p0 & 31;
            const float xa[4] = {xv.x, xv.y, xv.z, xv.w};
#pragma unroll
            for (int k = 0; k < 4; k++) {
                const float xval = xa[k];
                const int w = w0 + k;
#pragma unroll
                for (int ii = 0; ii < 3; ii++) {
                    const int hh = h - (ii - 1);
                    if (hh < 0 || hh > 31) continue;
#pragma unroll
                    for (int j = 0; j < 3; j++) {
                        const int ww = w - (j - 1);
                        if (ww < 0 || ww > 31) continue;
                        acc[ii * 3 + j] += xval * lw[hh * 32 + ww];
                    }
                }
            }
            acc[9] = lv.x + lv.y + lv.z + lv.w;

#pragma unroll
            for (int k = 0; k < 10; k++) {
#pragma unroll
                for (int m = 1; m < 64; m <<= 1) acc[k] += __shfl_xor(acc[k], m, 64);
            }
            if (ln == 0) {
#pragma unroll
                for (int k = 0; k < 10; k++) red[k][wv] = acc[k];
            }
            __syncthreads();
            if (tid < 10) Tsh[tid] = red[tid][0] + red[tid][1] + red[tid][2] + red[tid][3];
            __syncthreads();

            if (tid < E) {
                const int e = tid;
                float val = lin_b[31] + conv_b[e] * Tsh[9];
#pragma unroll
                for (int k = 0; k < 9; k++) val += conv_w[e * 9 + k] * Tsh[k];
                ush[e] = val;
            }
            __syncthreads();

            xml[i][tid] = dot128(W_in + (size_t)tid * E, ush);
            if (i >= 3) zg[b * DI + tid] = dot128(W_in + (size_t)(tid + 256) * E, ush);
            __syncthreads();   // ush/Tsh/red reused next iteration
        }

        // conv1d (K=4, causal) + silu -> xs
        {
            const float4 wc = ((const float4*)c1w)[tid];
            const float cb = conv1d_b[tid];
#pragma unroll
            for (int r = 0; r < 4; r++) {
                const int b = bb + r;
                float a = cb;
                if (b >= 3) a += xml[r + 0][tid] * wc.x;
                if (b >= 2) a += xml[r + 1][tid] * wc.y;
                if (b >= 1) a += xml[r + 2][tid] * wc.z;
                a += xml[r + 3][tid] * wc.w;
                const float s = silu_f(a);
                xs_sh[r][tid] = s;
                xs_g[b * DI + tid] = s;
            }
        }
        __syncthreads();

        // W_x projection (direct row reads; same ascending-c accumulation)
        for (int jj = tid; jj < JWX; jj += 256) {
            const float4* wr = (const float4*)(W_x + (size_t)jj * DI);
            float a0 = 0.f, a1 = 0.f, a2 = 0.f, a3 = 0.f;
#pragma unroll 8
            for (int c4 = 0; c4 < 64; c4++) {
                const float4 w = wr[c4];
                a0 += xs_sh[0][4*c4]*w.x + xs_sh[0][4*c4+1]*w.y + xs_sh[0][4*c4+2]*w.z + xs_sh[0][4*c4+3]*w.w;
                a1 += xs_sh[1][4*c4]*w.x + xs_sh[1][4*c4+1]*w.y + xs_sh[1][4*c4+2]*w.z + xs_sh[1][4*c4+3]*w.w;
                a2 += xs_sh[2][4*c4]*w.x + xs_sh[2][4*c4+1]*w.y + xs_sh[2][4*c4+2]*w.z + xs_sh[2][4*c4+3]*w.w;
                a3 += xs_sh[3][4*c4]*w.x + xs_sh[3][4*c4+1]*w.y + xs_sh[3][4*c4+2]*w.z + xs_sh[3][4*c4+3]*w.w;
            }
            const float av[4] = {a0, a1, a2, a3};
#pragma unroll
            for (int r = 0; r < 4; r++) {
                const int b = bb + r;
                if (jj < DTR)          dtin[r][jj] = av[r];
                else if (jj < DTR + S) Bm[b * S + (jj - DTR)] = av[r];
                else                   Cm[b * S + (jj - DTR - S)] = av[r];
            }
        }
        __syncthreads();

        // delta = softplus(dtin @ W_dt.T + b_dt)
        {
            const int d = tid;
            const float bd = b_dt[d];
            const float4 wd0 = ((const float4*)(W_dt + d * DTR))[0];
            const float4 wd1 = ((const float4*)(W_dt + d * DTR))[1];
#pragma unroll
            for (int r2 = 0; r2 < 4; r2++) {
                float a = bd
                    + dtin[r2][0]*wd0.x + dtin[r2][1]*wd0.y + dtin[r2][2]*wd0.z + dtin[r2][3]*wd0.w
                    + dtin[r2][4]*wd1.x + dtin[r2][5]*wd1.y + dtin[r2][6]*wd1.z + dtin[r2][7]*wd1.w;
                delta_g[(bb + r2) * DI + d] = (a > 20.0f) ? a : log1pf(__expf(a));
            }
        }

        // zero this chunk's DOWN-arrival counter (before rowflag release)
        if (tid == 0) st_flag(&donecnt[(g >> 2) * 16], 0);
        __syncthreads();                 // drains all waves' vmem (compiler waitcnt)
        if (tid == 0) {
            __threadfence();             // L2 writeback -> agent visible
            st_flag(&rowflag[g], SENT);
        }
    }

    // ---------------- UP: columns xp = bid&63, chunks bid>>6 + 8k ------------
    const int xp = bid & 63;
    const int d  = xp * 4 + wv;
    const int s0 = ln * 4;

    const float4 al = *(const float4*)(A_log + d * S + s0);
    float4 A;
    A.x = -__expf(al.x); A.y = -__expf(al.y);
    A.z = -__expf(al.z); A.w = -__expf(al.w);

    for (int k = 0; k < 4; k++) {
        const int c = (bid >> 6) + 8 * k;
        const int t0 = c * TCV;

        if (tid == 0) {
            for (int g2 = 4 * c; g2 < 4 * c + 4; g2++)
                while (ld_flag(&rowflag[g2]) != SENT) __builtin_amdgcn_s_sleep(8);
            acq_fence();
        }
        __syncthreads();

        float4 h = make_float4(0.f, 0.f, 0.f, 0.f);
        float cd = 0.0f;
        for (int tb = 0; tb < TCV; tb += 8) {
#pragma unroll
            for (int i = 0; i < 8; i++) {
                const int tt = t0 + tb + i;
                const float dd = delta_g[tt * DI + d];
                cd += dd;
                const float u = dd * xs_g[tt * DI + d];
                const float4 B = *(const float4*)(Bm + tt * S + s0);
                h.x = __expf(dd * A.x) * h.x + u * B.x;
                h.y = __expf(dd * A.y) * h.y + u * B.y;
                h.z = __expf(dd * A.z) * h.z + u * B.z;
                h.w = __expf(dd * A.w) * h.w + u * B.w;
            }
        }
        *(float4*)(hloc + ((size_t)(c * DI + d)) * S + s0) = h;
        if (ln == 0) Dchunk[c * DI + d] = cd;

        __syncthreads();                 // drain hloc/Dchunk stores (all waves)
        if (tid == 0) {
            __threadfence();
            st_flag(&upflag[c * 64 + xp], SENT);
        }
    }

    // ---------------- DOWN: same columns, ascending c ------------------------
    for (int k = 0; k < 4; k++) {
        const int c = (bid >> 6) + 8 * k;
        const int t0 = c * TCV;

        if (tid == 0) {
            for (int cp = 0; cp < c; cp++)
                while (ld_flag(&upflag[cp * 64 + xp]) != SENT) __builtin_amdgcn_s_sleep(8);
            acq_fence();
        }
        __syncthreads();

        float4 h = make_float4(0.f, 0.f, 0.f, 0.f);
        for (int cp = 1; cp <= c; cp++) {
            const float4 hl = *(const float4*)(hloc + ((size_t)((cp - 1) * DI + d)) * S + s0);
            const float Dc = Dchunk[(cp - 1) * DI + d];
            h.x = hl.x + __expf(A.x * Dc) * h.x;
            h.y = hl.y + __expf(A.y * Dc) * h.y;
            h.z = hl.z + __expf(A.z * Dc) * h.z;
            h.w = hl.w + __expf(A.w * Dc) * h.w;
        }

        float pr[8];
        for (int tb = 0; tb < TCV; tb += 8) {
#pragma unroll
            for (int i = 0; i < 8; i++) {
                const int tt = t0 + tb + i;
                const float dd = delta_g[tt * DI + d];
                const float u = dd * xs_g[tt * DI + d];
                const float4 B = *(const float4*)(Bm + tt * S + s0);
                const float4 C = *(const float4*)(Cm + tt * S + s0);
                h.x = __expf(dd * A.x) * h.x + u * B.x;
                h.y = __expf(dd * A.y) * h.y + u * B.y;
                h.z = __expf(dd * A.z) * h.z + u * B.z;
                h.w = __expf(dd * A.w) * h.w + u * B.w;
                pr[i] = h.x * C.x + h.y * C.y + h.z * C.z + h.w * C.w;
            }
#pragma unroll
            for (int i = 0; i < 8; i++) {
#pragma unroll
                for (int m = 1; m < 64; m <<= 1) pr[i] += __shfl_xor(pr[i], m, 64);
            }
            if (ln == 0) {
#pragma unroll
                for (int i = 0; i < 8; i++) y[(t0 + tb + i) * DI + d] = pr[i];
            }
        }

        __syncthreads();                 // drain y stores (all waves)
        if (tid == 0) {
            __threadfence();
            __hip_atomic_fetch_add(&donecnt[c * 16], 1,
                                   __ATOMIC_RELAXED, __HIP_MEMORY_SCOPE_AGENT);
        }
    }

    // ---------------- HEADS: blocks 256..511, batch pair v = bid-256 ---------
    if (bid >= 256) {
        const int v = bid - 256;
        const int bb = v * 2;
        const int c = bb >> 4;           // chunk containing rows bb, bb+1 (TCV=16)

        if (tid == 0) {
            while (ld_flag(&donecnt[c * 16]) != 64) __builtin_amdgcn_s_sleep(8);
            acq_fence();
        }
        __syncthreads();

        for (int idx = tid; idx < 2 * DI; idx += 256) {
            const int r = idx >> 8, cc = idx & 255;
            const int b = bb + r;
            const float z = zg[b * DI + cc];
            yf[r][cc] = (y[b * DI + cc] + xs_g[b * DI + cc] * Dp[cc]) * silu_f(z);
        }
        __syncthreads();
        {
            const int r = tid >> 7, e = tid & 127;
            const float4* wr = (const float4*)(W_out + (size_t)e * DI);
            float a = 0.0f;
#pragma unroll 8
            for (int d4 = 0; d4 < 64; d4++) {
                const float4 w = wr[d4];
                a += yf[r][4*d4]*w.x + yf[r][4*d4+1]*w.y + yf[r][4*d4+2]*w.z + yf[r][4*d4+3]*w.w;
            }
            feat[r][e] = a;
        }
        __syncthreads();
        if (tid < 16) {
            const int r = tid >> 3, hd = tid & 7;
            const int b = bb + r;
            const float* wrow;
            float bias;
            int dst;
            if (hd == 0)      { wrow = We;                 bias = be[0];      dst = b; }
            else if (hd < 4)  { wrow = Wa + (hd - 1) * E;  bias = ba[hd - 1]; dst = 512 + b * 3 + (hd - 1); }
            else              { wrow = Wq + (hd - 4) * E;  bias = bq[hd - 4]; dst = 2048 + b * 4 + (hd - 4); }
            float a = bias;
#pragma unroll 4
            for (int e = 0; e < E; e++) a += feat[r][e] * wrow[e];
            out[dst] = a;
        }
    }
}

// ===========================================================================
extern "C" void kernel_launch(void* const* d_in, const int* in_sizes, int n_in,
                              void* d_out, int out_size, void* d_ws, size_t ws_size,
                              hipStream_t stream)
{
    const float* x        = (const float*)d_in[0];
    const float* conv_w   = (const float*)d_in[1];
    const float* conv_b   = (const float*)d_in[2];
    const float* lin_w    = (const float*)d_in[3];
    const float* lin_b    = (const float*)d_in[4];
    const float* W_in     = (const float*)d_in[5];
    const float* conv1d_w = (const float*)d_in[6];
    const float* conv1d_b = (const float*)d_in[7];
    const float* W_x      = (const float*)d_in[8];
    const float* W_dt     = (const float*)d_in[9];
    const float* b_dt     = (const float*)d_in[10];
    const float* A_log    = (const float*)d_in[11];
    const float* Dp       = (const float*)d_in[12];
    const float* W_out    = (const float*)d_in[13];
    const float* We       = (const float*)d_in[14];
    const float* be       = (const float*)d_in[15];
    const float* Wa       = (const float*)d_in[16];
    const float* ba       = (const float*)d_in[17];
    const float* Wq       = (const float*)d_in[18];
    const float* bq       = (const float*)d_in[19];
    float* out = (float*)d_out;

    float* ws = (float*)d_ws;
    float* zg     = ws;                     // 512*256 each
    float* xs     = zg     + 512 * 256;
    float* delta  = xs     + 512 * 256;
    float* Bm     = delta  + 512 * 256;
    float* Cm     = Bm     + 512 * 256;
    float* y      = Cm     + 512 * 256;
    float* hloc   = y      + 512 * 256;     // NC*DI*S
    float* Dchunk = hloc   + (size_t)NC * DI * S;    // NC*DI
    int*   flags  = (int*)(Dchunk + NC * DI);
    int*   rowflag = flags;                 // 128
    int*   upflag  = flags + 128;           // NC*64 = 2048
    int*   donecnt = flags + 128 + 2048;    // NC*16 = 512 (64B-strided)

    mega<<<NBLK, 256, 0, stream>>>(
        x, conv_w, conv_b, lin_w, lin_b, W_in,
        conv1d_w, conv1d_b, W_x, W_dt, b_dt, A_log, Dp, W_out,
        We, be, Wa, ba, Wq, bq, out,
        zg, xs, delta, Bm, Cm, y, hloc, Dchunk,
        rowflag, upflag, donecnt);
}

// Round 5
// 293.352 us; speedup vs baseline: 2.2771x; 1.2480x over previous
//
#include <hip/hip_runtime.h>
#include <math.h>

// Sizes (fixed by the problem)
#define BATCH 512   // scan sequence length (original batch dim)
#define E     128
#define DI    256
#define S     256
#define DTR   8
#define KCONV 4
#define JWX   520   // dt(8) + B(256) + C(256)
#define NBLK  512   // persistent grid: 2 blocks/CU x 256 CU (residency proven R3/R4)
#define SENT  0x7C3A91E5   // "task done" sentinel; != any plausible poison fill

__device__ __forceinline__ float silu_f(float v) {
    return v / (1.0f + __expf(-v));
}

__device__ __forceinline__ int ld_flag(const int* p) {
    return __hip_atomic_load(p, __ATOMIC_RELAXED, __HIP_MEMORY_SCOPE_AGENT);
}
__device__ __forceinline__ void st_flag(int* p, int v) {
    __hip_atomic_store(p, v, __ATOMIC_RELAXED, __HIP_MEMORY_SCOPE_AGENT);
}
__device__ __forceinline__ void acq_fence() {
    __builtin_amdgcn_fence(__ATOMIC_ACQUIRE, "agent");   // L1(+L2) invalidate
}

__device__ __forceinline__ float dot128(const float* __restrict__ w,
                                        const float* __restrict__ u) {
    const float4* wp = (const float4*)w;
    float a = 0.0f;
#pragma unroll 8
    for (int e4 = 0; e4 < 32; e4++) {
        const float4 ww = wp[e4];
        a += u[4*e4]*ww.x + u[4*e4+1]*ww.y + u[4*e4+2]*ww.z + u[4*e4+3]*ww.w;
    }
    return a;
}

// ===========================================================================
// MEGA persistent kernel, 3-stage data-flow:
//   blocks   0..127 : P01  (conv2d+lin -> u -> W_in -> conv1d -> W_x -> delta)
//                     for batch group g=bid (4 rows + 3 recomputed xm rows)
//                     -> rowflag[g]
//   blocks 128..191 : SCAN column xp=bid-128: wait all rowflags, then ONE
//                     serial pass t=0..511 (exact reference recurrence order;
//                     dependent chain = 1 FMA/step, loads/exps pipeline)
//                     -> scanflag[xp].  No hloc/carry/up-down machinery.
//   blocks 256..511 : HEADS batch pair v=bid-256: wait all scanflags.
//   blocks 192..255 : exit.
// Release: all-wave s_waitcnt(0) -> syncthreads -> tid0 threadfence(wbl2) ->
//          relaxed SENT store. Consume: parallel per-thread poll ->
//          syncthreads -> all-wave acquire fence.
// ===========================================================================
__global__ __launch_bounds__(256, 2) void mega(
    const float* __restrict__ x, const float* __restrict__ conv_w,
    const float* __restrict__ conv_b, const float* __restrict__ lin_w,
    const float* __restrict__ lin_b, const float* __restrict__ W_in,
    const float* __restrict__ c1w, const float* __restrict__ conv1d_b,
    const float* __restrict__ W_x, const float* __restrict__ W_dt,
    const float* __restrict__ b_dt, const float* __restrict__ A_log,
    const float* __restrict__ Dp, const float* __restrict__ W_out,
    const float* __restrict__ We, const float* __restrict__ be,
    const float* __restrict__ Wa, const float* __restrict__ ba,
    const float* __restrict__ Wq, const float* __restrict__ bq,
    float* __restrict__ out,
    float* __restrict__ zg, float* __restrict__ xs_g,
    float* __restrict__ delta_g, float* __restrict__ Bm,
    float* __restrict__ Cm, float* __restrict__ y,
    int* __restrict__ rowflag, int* __restrict__ scanflag)
{
    const int tid = threadIdx.x;
    const int bid = blockIdx.x;
    const int wv = tid >> 6, ln = tid & 63;

    __shared__ float lw[1024];
    __shared__ float red[10][4];
    __shared__ float Tsh[10];
    __shared__ float ush[E];
    __shared__ float xml[7][DI];
    __shared__ float xs_sh[4][DI];
    __shared__ float dtin[4][8];
    __shared__ float yf[2][DI];
    __shared__ float feat[2][E];

    // ---------------- P01: batch group g = bid (bid < 128) -------------------
    if (bid < 128) {
        const int g = bid, bb = g * 4;

        const float4 lv = ((const float4*)(lin_w + 31 * 1024))[tid];
        ((float4*)lw)[tid] = lv;
        __syncthreads();

        for (int i = 0; i < 7; i++) {          // rows bb-3 .. bb+3
            const int b = bb - 3 + i;
            if (b < 0) continue;               // block-uniform

            float acc[10];
#pragma unroll
            for (int k = 0; k < 10; k++) acc[k] = 0.0f;

            const float4 xv = ((const float4*)(x + (size_t)b * 1024))[tid];
            const int p0 = tid * 4;
            const int h = p0 >> 5, w0 = p0 & 31;
            const float xa[4] = {xv.x, xv.y, xv.z, xv.w};
#pragma unroll
            for (int k = 0; k < 4; k++) {
                const float xval = xa[k];
                const int w = w0 + k;
#pragma unroll
                for (int ii = 0; ii < 3; ii++) {
                    const int hh = h - (ii - 1);
                    if (hh < 0 || hh > 31) continue;
#pragma unroll
                    for (int j = 0; j < 3; j++) {
                        const int ww = w - (j - 1);
                        if (ww < 0 || ww > 31) continue;
                        acc[ii * 3 + j] += xval * lw[hh * 32 + ww];
                    }
                }
            }
            acc[9] = lv.x + lv.y + lv.z + lv.w;

#pragma unroll
            for (int k = 0; k < 10; k++) {
#pragma unroll
                for (int m = 1; m < 64; m <<= 1) acc[k] += __shfl_xor(acc[k], m, 64);
            }
            if (ln == 0) {
#pragma unroll
                for (int k = 0; k < 10; k++) red[k][wv] = acc[k];
            }
            __syncthreads();
            if (tid < 10) Tsh[tid] = red[tid][0] + red[tid][1] + red[tid][2] + red[tid][3];
            __syncthreads();

            if (tid < E) {
                const int e = tid;
                float val = lin_b[31] + conv_b[e] * Tsh[9];
#pragma unroll
                for (int k = 0; k < 9; k++) val += conv_w[e * 9 + k] * Tsh[k];
                ush[e] = val;
            }
            __syncthreads();

            xml[i][tid] = dot128(W_in + (size_t)tid * E, ush);
            if (i >= 3) zg[b * DI + tid] = dot128(W_in + (size_t)(tid + 256) * E, ush);
            __syncthreads();   // ush/Tsh/red reused next iteration
        }

        // conv1d (K=4, causal) + silu -> xs
        {
            const float4 wc = ((const float4*)c1w)[tid];
            const float cb = conv1d_b[tid];
#pragma unroll
            for (int r = 0; r < 4; r++) {
                const int b = bb + r;
                float a = cb;
                if (b >= 3) a += xml[r + 0][tid] * wc.x;
                if (b >= 2) a += xml[r + 1][tid] * wc.y;
                if (b >= 1) a += xml[r + 2][tid] * wc.z;
                a += xml[r + 3][tid] * wc.w;
                const float s = silu_f(a);
                xs_sh[r][tid] = s;
                xs_g[b * DI + tid] = s;
            }
        }
        __syncthreads();

        // W_x projection (direct row reads)
        for (int jj = tid; jj < JWX; jj += 256) {
            const float4* wr = (const float4*)(W_x + (size_t)jj * DI);
            float a0 = 0.f, a1 = 0.f, a2 = 0.f, a3 = 0.f;
#pragma unroll 8
            for (int c4 = 0; c4 < 64; c4++) {
                const float4 w = wr[c4];
                a0 += xs_sh[0][4*c4]*w.x + xs_sh[0][4*c4+1]*w.y + xs_sh[0][4*c4+2]*w.z + xs_sh[0][4*c4+3]*w.w;
                a1 += xs_sh[1][4*c4]*w.x + xs_sh[1][4*c4+1]*w.y + xs_sh[1][4*c4+2]*w.z + xs_sh[1][4*c4+3]*w.w;
                a2 += xs_sh[2][4*c4]*w.x + xs_sh[2][4*c4+1]*w.y + xs_sh[2][4*c4+2]*w.z + xs_sh[2][4*c4+3]*w.w;
                a3 += xs_sh[3][4*c4]*w.x + xs_sh[3][4*c4+1]*w.y + xs_sh[3][4*c4+2]*w.z + xs_sh[3][4*c4+3]*w.w;
            }
            const float av[4] = {a0, a1, a2, a3};
#pragma unroll
            for (int r = 0; r < 4; r++) {
                const int b = bb + r;
                if (jj < DTR)          dtin[r][jj] = av[r];
                else if (jj < DTR + S) Bm[b * S + (jj - DTR)] = av[r];
                else                   Cm[b * S + (jj - DTR - S)] = av[r];
            }
        }
        __syncthreads();

        // delta = softplus(dtin @ W_dt.T + b_dt)
        {
            const int d = tid;
            const float bd = b_dt[d];
            const float4 wd0 = ((const float4*)(W_dt + d * DTR))[0];
            const float4 wd1 = ((const float4*)(W_dt + d * DTR))[1];
#pragma unroll
            for (int r2 = 0; r2 < 4; r2++) {
                float a = bd
                    + dtin[r2][0]*wd0.x + dtin[r2][1]*wd0.y + dtin[r2][2]*wd0.z + dtin[r2][3]*wd0.w
                    + dtin[r2][4]*wd1.x + dtin[r2][5]*wd1.y + dtin[r2][6]*wd1.z + dtin[r2][7]*wd1.w;
                delta_g[(bb + r2) * DI + d] = (a > 20.0f) ? a : log1pf(__expf(a));
            }
        }

        // release: all stores in L2 (write-through + vmcnt0) -> wbl2 -> flag
        __builtin_amdgcn_s_waitcnt(0);
        __syncthreads();
        if (tid == 0) {
            __threadfence();             // L2 writeback -> agent visible
            st_flag(&rowflag[g], SENT);
        }
        return;
    }

    // ---------------- SCAN: blocks 128..191, column xp = bid-128 -------------
    if (bid < 192) {
        const int xp = bid - 128;
        const int d  = xp * 4 + wv;
        const int s0 = ln * 4;

        // parallel wait for all 128 P01 groups
        if (tid < 128) {
            while (ld_flag(&rowflag[tid]) != SENT) __builtin_amdgcn_s_sleep(2);
        }
        __syncthreads();
        acq_fence();                     // all waves: invalidate stale lines
        __syncthreads();

        const float4 al = *(const float4*)(A_log + d * S + s0);
        float4 A;
        A.x = -__expf(al.x); A.y = -__expf(al.y);
        A.z = -__expf(al.z); A.w = -__expf(al.w);

        float4 h = make_float4(0.f, 0.f, 0.f, 0.f);
        for (int tb = 0; tb < BATCH; tb += 8) {
            float pr[8];
#pragma unroll
            for (int i = 0; i < 8; i++) {
                const int tt = tb + i;
                const float dd = delta_g[tt * DI + d];
                const float u  = dd * xs_g[tt * DI + d];
                const float4 B = *(const float4*)(Bm + tt * S + s0);
                const float4 C = *(const float4*)(Cm + tt * S + s0);
                h.x = __expf(dd * A.x) * h.x + u * B.x;
                h.y = __expf(dd * A.y) * h.y + u * B.y;
                h.z = __expf(dd * A.z) * h.z + u * B.z;
                h.w = __expf(dd * A.w) * h.w + u * B.w;
                pr[i] = h.x * C.x + h.y * C.y + h.z * C.z + h.w * C.w;
            }
#pragma unroll
            for (int i = 0; i < 8; i++) {
#pragma unroll
                for (int m = 1; m < 64; m <<= 1) pr[i] += __shfl_xor(pr[i], m, 64);
            }
            if (ln == 0) {
#pragma unroll
                for (int i = 0; i < 8; i++) y[(tb + i) * DI + d] = pr[i];
            }
        }

        __builtin_amdgcn_s_waitcnt(0);
        __syncthreads();
        if (tid == 0) {
            __threadfence();
            st_flag(&scanflag[xp], SENT);
        }
        return;
    }

    if (bid < 256) return;               // idle blocks

    // ---------------- HEADS: blocks 256..511, batch pair v = bid-256 ---------
    {
        const int v = bid - 256;
        const int bb = v * 2;

        if (tid < 64) {
            while (ld_flag(&scanflag[tid]) != SENT) __builtin_amdgcn_s_sleep(2);
        }
        __syncthreads();
        acq_fence();
        __syncthreads();

        for (int idx = tid; idx < 2 * DI; idx += 256) {
            const int r = idx >> 8, cc = idx & 255;
            const int b = bb + r;
            const float z = zg[b * DI + cc];
            yf[r][cc] = (y[b * DI + cc] + xs_g[b * DI + cc] * Dp[cc]) * silu_f(z);
        }
        __syncthreads();
        {
            const int r = tid >> 7, e = tid & 127;
            const float4* wr = (const float4*)(W_out + (size_t)e * DI);
            float a = 0.0f;
#pragma unroll 8
            for (int d4 = 0; d4 < 64; d4++) {
                const float4 w = wr[d4];
                a += yf[r][4*d4]*w.x + yf[r][4*d4+1]*w.y + yf[r][4*d4+2]*w.z + yf[r][4*d4+3]*w.w;
            }
            feat[r][e] = a;
        }
        __syncthreads();
        if (tid < 16) {
            const int r = tid >> 3, hd = tid & 7;
            const int b = bb + r;
            const float* wrow;
            float bias;
            int dst;
            if (hd == 0)      { wrow = We;                 bias = be[0];      dst = b; }
            else if (hd < 4)  { wrow = Wa + (hd - 1) * E;  bias = ba[hd - 1]; dst = 512 + b * 3 + (hd - 1); }
            else              { wrow = Wq + (hd - 4) * E;  bias = bq[hd - 4]; dst = 2048 + b * 4 + (hd - 4); }
            float a = bias;
#pragma unroll 4
            for (int e = 0; e < E; e++) a += feat[r][e] * wrow[e];
            out[dst] = a;
        }
    }
}

// ===========================================================================
extern "C" void kernel_launch(void* const* d_in, const int* in_sizes, int n_in,
                              void* d_out, int out_size, void* d_ws, size_t ws_size,
                              hipStream_t stream)
{
    const float* x        = (const float*)d_in[0];
    const float* conv_w   = (const float*)d_in[1];
    const float* conv_b   = (const float*)d_in[2];
    const float* lin_w    = (const float*)d_in[3];
    const float* lin_b    = (const float*)d_in[4];
    const float* W_in     = (const float*)d_in[5];
    const float* conv1d_w = (const float*)d_in[6];
    const float* conv1d_b = (const float*)d_in[7];
    const float* W_x      = (const float*)d_in[8];
    const float* W_dt     = (const float*)d_in[9];
    const float* b_dt     = (const float*)d_in[10];
    const float* A_log    = (const float*)d_in[11];
    const float* Dp       = (const float*)d_in[12];
    const float* W_out    = (const float*)d_in[13];
    const float* We       = (const float*)d_in[14];
    const float* be       = (const float*)d_in[15];
    const float* Wa       = (const float*)d_in[16];
    const float* ba       = (const float*)d_in[17];
    const float* Wq       = (const float*)d_in[18];
    const float* bq       = (const float*)d_in[19];
    float* out = (float*)d_out;

    float* ws = (float*)d_ws;
    float* zg     = ws;                     // 512*256 each
    float* xs     = zg     + 512 * 256;
    float* delta  = xs     + 512 * 256;
    float* Bm     = delta  + 512 * 256;
    float* Cm     = Bm     + 512 * 256;
    float* y      = Cm     + 512 * 256;
    int*   flags  = (int*)(y + 512 * 256);
    int*   rowflag  = flags;                // 128
    int*   scanflag = flags + 128;          // 64

    mega<<<NBLK, 256, 0, stream>>>(
        x, conv_w, conv_b, lin_w, lin_b, W_in,
        conv1d_w, conv1d_b, W_x, W_dt, b_dt, A_log, Dp, W_out,
        We, be, Wa, ba, Wq, bq, out,
        zg, xs, delta, Bm, Cm, y,
        rowflag, scanflag);
}

// Round 6
// 287.300 us; speedup vs baseline: 2.3251x; 1.0211x over previous
//
#include <hip/hip_runtime.h>
#include <math.h>

// Sizes (fixed by the problem)
#define BATCH 512   // scan sequence length (original batch dim)
#define E     128
#define DI    256
#define S     256
#define DTR   8
#define KCONV 4
#define JWX   520   // dt(8) + B(256) + C(256)
#define NBLK  512   // persistent grid: 2 blocks/CU x 256 CU (residency proven R3-R5)
#define SENT  0x7C3A91E5

__device__ __forceinline__ float silu_f(float v) {
    return v / (1.0f + __expf(-v));
}

__device__ __forceinline__ int ld_flag(const int* p) {
    return __hip_atomic_load(p, __ATOMIC_RELAXED, __HIP_MEMORY_SCOPE_AGENT);
}
__device__ __forceinline__ void st_flag(int* p, int v) {
    __hip_atomic_store(p, v, __ATOMIC_RELAXED, __HIP_MEMORY_SCOPE_AGENT);
}
__device__ __forceinline__ void acq_fence() {
    __builtin_amdgcn_fence(__ATOMIC_ACQUIRE, "agent");   // L1/L2 invalidate
}
__device__ __forceinline__ float ld_bypass(const float* p) {
    // relaxed agent atomic load: bypasses L1/L2, reads MALL-visible data
    return __int_as_float(__hip_atomic_load((const int*)p,
                         __ATOMIC_RELAXED, __HIP_MEMORY_SCOPE_AGENT));
}

__device__ __forceinline__ float dot128(const float* __restrict__ w,
                                        const float* __restrict__ u) {
    const float4* wp = (const float4*)w;
    float a = 0.0f;
#pragma unroll 8
    for (int e4 = 0; e4 < 32; e4++) {
        const float4 ww = wp[e4];
        a += u[4*e4]*ww.x + u[4*e4+1]*ww.y + u[4*e4+2]*ww.z + u[4*e4+3]*ww.w;
    }
    return a;
}

// ===========================================================================
// MEGA persistent kernel, counter data-flow, single-lane polls.
//   blocks   0..127 : P0 (conv2d rows 4g..4g+3 -> xm,zg) -> xmflag[g]
//                     P1 (3 neighbor xm rows via bypass loads -> conv1d ->
//                     W_x -> delta/Bm/Cm) -> rowdone++
//   blocks 128..383 : SCAN (xp = idx&63 -> d-quad, q = idx>>6 -> s-quarter);
//                     wait rowdone==128; serial t=0..511; 64-lane reduce ->
//                     y_part[q]  -> scandone++
//   blocks 384..511 : HEADS (4 rows each); wait scandone==256; sum quarters.
// All polls: tid==0, ONE address, s_sleep between rounds (no poll storm).
// Counters init'd by block 0 behind SENT initflag (poison-safe).
// ===========================================================================
__global__ __launch_bounds__(256, 2) void mega(
    const float* __restrict__ x, const float* __restrict__ conv_w,
    const float* __restrict__ conv_b, const float* __restrict__ lin_w,
    const float* __restrict__ lin_b, const float* __restrict__ W_in,
    const float* __restrict__ c1w, const float* __restrict__ conv1d_b,
    const float* __restrict__ W_x, const float* __restrict__ W_dt,
    const float* __restrict__ b_dt, const float* __restrict__ A_log,
    const float* __restrict__ Dp, const float* __restrict__ W_out,
    const float* __restrict__ We, const float* __restrict__ be,
    const float* __restrict__ Wa, const float* __restrict__ ba,
    const float* __restrict__ Wq, const float* __restrict__ bq,
    float* __restrict__ out,
    float* __restrict__ zg, float* __restrict__ xs_g,
    float* __restrict__ delta_g, float* __restrict__ Bm,
    float* __restrict__ Cm, float* __restrict__ xmg,
    float* __restrict__ ypart,
    int* __restrict__ initflag, int* __restrict__ rowdone,
    int* __restrict__ scandone, int* __restrict__ xmflag)
{
    const int tid = threadIdx.x;
    const int bid = blockIdx.x;
    const int wv = tid >> 6, ln = tid & 63;

    __shared__ float lw[1024];
    __shared__ float red[10][4];
    __shared__ float Tsh[10];
    __shared__ float ush[E];
    __shared__ float xml[7][DI];
    __shared__ float xs_sh[4][DI];
    __shared__ float dtin[4][8];
    __shared__ float yf[4][DI];
    __shared__ float feat[4][E];

    if (bid == 0 && tid == 0) {
        st_flag(rowdone, 0);
        st_flag(scandone, 0);
        __threadfence();
        st_flag(initflag, SENT);
    }

    // ================= P0 + P1 : blocks 0..127 ==============================
    if (bid < 128) {
        const int g = bid, bb = g * 4;

        const float4 lv = ((const float4*)(lin_w + 31 * 1024))[tid];
        ((float4*)lw)[tid] = lv;
        __syncthreads();

        // ---- P0: conv2d+lin rows bb..bb+3 -> xm (LDS+global), zg
        for (int r = 0; r < 4; r++) {
            const int b = bb + r;

            float acc[10];
#pragma unroll
            for (int k = 0; k < 10; k++) acc[k] = 0.0f;

            const float4 xv = ((const float4*)(x + (size_t)b * 1024))[tid];
            const int p0 = tid * 4;
            const int h = p0 >> 5, w0 = p0 & 31;
            const float xa[4] = {xv.x, xv.y, xv.z, xv.w};
#pragma unroll
            for (int k = 0; k < 4; k++) {
                const float xval = xa[k];
                const int w = w0 + k;
#pragma unroll
                for (int ii = 0; ii < 3; ii++) {
                    const int hh = h - (ii - 1);
                    if (hh < 0 || hh > 31) continue;
#pragma unroll
                    for (int j = 0; j < 3; j++) {
                        const int ww = w - (j - 1);
                        if (ww < 0 || ww > 31) continue;
                        acc[ii * 3 + j] += xval * lw[hh * 32 + ww];
                    }
                }
            }
            acc[9] = lv.x + lv.y + lv.z + lv.w;

#pragma unroll
            for (int k = 0; k < 10; k++) {
#pragma unroll
                for (int m = 1; m < 64; m <<= 1) acc[k] += __shfl_xor(acc[k], m, 64);
            }
            if (ln == 0) {
#pragma unroll
                for (int k = 0; k < 10; k++) red[k][wv] = acc[k];
            }
            __syncthreads();
            if (tid < 10) Tsh[tid] = red[tid][0] + red[tid][1] + red[tid][2] + red[tid][3];
            __syncthreads();

            if (tid < E) {
                const int e = tid;
                float val = lin_b[31] + conv_b[e] * Tsh[9];
#pragma unroll
                for (int k = 0; k < 9; k++) val += conv_w[e * 9 + k] * Tsh[k];
                ush[e] = val;
            }
            __syncthreads();

            const float xmv = dot128(W_in + (size_t)tid * E, ush);
            xml[3 + r][tid] = xmv;
            xmg[b * DI + tid] = xmv;
            zg[b * DI + tid] = dot128(W_in + (size_t)(tid + 256) * E, ush);
            __syncthreads();   // ush/Tsh/red reused next row
        }

        // publish xm rows
        __syncthreads();
        if (tid == 0) {
            __threadfence();
            st_flag(&xmflag[g], SENT);
        }

        // ---- P1: neighbor xm rows bb-3..bb-1 from block g-1 (bypass loads)
        if (g > 0) {
            if (tid == 0) {
                while (ld_flag(&xmflag[g - 1]) != SENT) __builtin_amdgcn_s_sleep(2);
            }
            __syncthreads();
#pragma unroll
            for (int i = 0; i < 3; i++)
                xml[i][tid] = ld_bypass(xmg + (size_t)(bb - 3 + i) * DI + tid);
        }
        __syncthreads();

        // conv1d (K=4, causal) + silu -> xs
        {
            const float4 wc = ((const float4*)c1w)[tid];
            const float cb = conv1d_b[tid];
#pragma unroll
            for (int r = 0; r < 4; r++) {
                const int b = bb + r;
                float a = cb;
                if (b >= 3) a += xml[r + 0][tid] * wc.x;
                if (b >= 2) a += xml[r + 1][tid] * wc.y;
                if (b >= 1) a += xml[r + 2][tid] * wc.z;
                a += xml[r + 3][tid] * wc.w;
                const float s = silu_f(a);
                xs_sh[r][tid] = s;
                xs_g[b * DI + tid] = s;
            }
        }
        __syncthreads();

        // W_x projection (direct row reads)
        for (int jj = tid; jj < JWX; jj += 256) {
            const float4* wr = (const float4*)(W_x + (size_t)jj * DI);
            float a0 = 0.f, a1 = 0.f, a2 = 0.f, a3 = 0.f;
#pragma unroll 8
            for (int c4 = 0; c4 < 64; c4++) {
                const float4 w = wr[c4];
                a0 += xs_sh[0][4*c4]*w.x + xs_sh[0][4*c4+1]*w.y + xs_sh[0][4*c4+2]*w.z + xs_sh[0][4*c4+3]*w.w;
                a1 += xs_sh[1][4*c4]*w.x + xs_sh[1][4*c4+1]*w.y + xs_sh[1][4*c4+2]*w.z + xs_sh[1][4*c4+3]*w.w;
                a2 += xs_sh[2][4*c4]*w.x + xs_sh[2][4*c4+1]*w.y + xs_sh[2][4*c4+2]*w.z + xs_sh[2][4*c4+3]*w.w;
                a3 += xs_sh[3][4*c4]*w.x + xs_sh[3][4*c4+1]*w.y + xs_sh[3][4*c4+2]*w.z + xs_sh[3][4*c4+3]*w.w;
            }
            const float av[4] = {a0, a1, a2, a3};
#pragma unroll
            for (int r = 0; r < 4; r++) {
                const int b = bb + r;
                if (jj < DTR)          dtin[r][jj] = av[r];
                else if (jj < DTR + S) Bm[b * S + (jj - DTR)] = av[r];
                else                   Cm[b * S + (jj - DTR - S)] = av[r];
            }
        }
        __syncthreads();

        // delta = softplus(dtin @ W_dt.T + b_dt)
        {
            const int d = tid;
            const float bd = b_dt[d];
            const float4 wd0 = ((const float4*)(W_dt + d * DTR))[0];
            const float4 wd1 = ((const float4*)(W_dt + d * DTR))[1];
#pragma unroll
            for (int r2 = 0; r2 < 4; r2++) {
                float a = bd
                    + dtin[r2][0]*wd0.x + dtin[r2][1]*wd0.y + dtin[r2][2]*wd0.z + dtin[r2][3]*wd0.w
                    + dtin[r2][4]*wd1.x + dtin[r2][5]*wd1.y + dtin[r2][6]*wd1.z + dtin[r2][7]*wd1.w;
                delta_g[(bb + r2) * DI + d] = (a > 20.0f) ? a : log1pf(__expf(a));
            }
        }

        __syncthreads();
        if (tid == 0) {
            __threadfence();
            while (ld_flag(initflag) != SENT) __builtin_amdgcn_s_sleep(1);
            __hip_atomic_fetch_add(rowdone, 1, __ATOMIC_RELAXED, __HIP_MEMORY_SCOPE_AGENT);
        }
        return;
    }

    // ================= SCAN : blocks 128..383 ===============================
    if (bid < 384) {
        const int idx2 = bid - 128;
        const int xp = idx2 & 63;       // d-quad
        const int q  = idx2 >> 6;       // s-quarter
        const int d  = xp * 4 + wv;
        const int s  = q * 64 + ln;

        if (tid == 0) {
            while (ld_flag(initflag) != SENT) __builtin_amdgcn_s_sleep(2);
            while (ld_flag(rowdone) < 128)    __builtin_amdgcn_s_sleep(8);
        }
        __syncthreads();
        acq_fence();                    // each wave invalidates, then reads fresh

        const float A = -__expf(A_log[d * S + s]);
        float h = 0.0f;
        float* yp = ypart + ((size_t)q * BATCH) * DI + d;

        for (int tb = 0; tb < BATCH; tb += 8) {
            float pr[8];
#pragma unroll
            for (int i = 0; i < 8; i++) {
                const int tt = tb + i;
                const float dd = delta_g[tt * DI + d];
                const float u  = dd * xs_g[tt * DI + d];
                const float bv = Bm[tt * S + s];
                const float cv = Cm[tt * S + s];
                h = __expf(dd * A) * h + u * bv;
                pr[i] = h * cv;
            }
#pragma unroll
            for (int i = 0; i < 8; i++) {
#pragma unroll
                for (int m = 1; m < 64; m <<= 1) pr[i] += __shfl_xor(pr[i], m, 64);
            }
            if (ln == 0) {
#pragma unroll
                for (int i = 0; i < 8; i++) yp[(tb + i) * DI] = pr[i];
            }
        }

        __syncthreads();
        if (tid == 0) {
            __threadfence();
            __hip_atomic_fetch_add(scandone, 1, __ATOMIC_RELAXED, __HIP_MEMORY_SCOPE_AGENT);
        }
        return;
    }

    // ================= HEADS : blocks 384..511 (4 rows each) ================
    {
        const int v = bid - 384;
        const int bb = v * 4;

        if (tid == 0) {
            while (ld_flag(initflag) != SENT) __builtin_amdgcn_s_sleep(2);
            while (ld_flag(scandone) < 256)   __builtin_amdgcn_s_sleep(8);
        }
        __syncthreads();
        acq_fence();

        for (int idx = tid; idx < 4 * DI; idx += 256) {
            const int r = idx >> 8, cc = idx & 255;
            const int b = bb + r;
            const float y0 = ypart[((size_t)0 * BATCH + b) * DI + cc];
            const float y1 = ypart[((size_t)1 * BATCH + b) * DI + cc];
            const float y2 = ypart[((size_t)2 * BATCH + b) * DI + cc];
            const float y3 = ypart[((size_t)3 * BATCH + b) * DI + cc];
            const float yv = (y0 + y1) + (y2 + y3);
            const float z = zg[b * DI + cc];
            yf[r][cc] = (yv + xs_g[b * DI + cc] * Dp[cc]) * silu_f(z);
        }
        __syncthreads();

        for (int it = 0; it < 2; it++) {
            const int r = (tid >> 7) + it * 2;
            const int e = tid & 127;
            const float4* wr = (const float4*)(W_out + (size_t)e * DI);
            float a = 0.0f;
#pragma unroll 8
            for (int d4 = 0; d4 < 64; d4++) {
                const float4 w = wr[d4];
                a += yf[r][4*d4]*w.x + yf[r][4*d4+1]*w.y + yf[r][4*d4+2]*w.z + yf[r][4*d4+3]*w.w;
            }
            feat[r][e] = a;
        }
        __syncthreads();

        if (tid < 32) {
            const int r = tid >> 3, hd = tid & 7;
            const int b = bb + r;
            const float* wrow;
            float bias;
            int dst;
            if (hd == 0)      { wrow = We;                 bias = be[0];      dst = b; }
            else if (hd < 4)  { wrow = Wa + (hd - 1) * E;  bias = ba[hd - 1]; dst = 512 + b * 3 + (hd - 1); }
            else              { wrow = Wq + (hd - 4) * E;  bias = bq[hd - 4]; dst = 2048 + b * 4 + (hd - 4); }
            float a = bias;
#pragma unroll 4
            for (int e = 0; e < E; e++) a += feat[r][e] * wrow[e];
            out[dst] = a;
        }
    }
}

// ===========================================================================
extern "C" void kernel_launch(void* const* d_in, const int* in_sizes, int n_in,
                              void* d_out, int out_size, void* d_ws, size_t ws_size,
                              hipStream_t stream)
{
    const float* x        = (const float*)d_in[0];
    const float* conv_w   = (const float*)d_in[1];
    const float* conv_b   = (const float*)d_in[2];
    const float* lin_w    = (const float*)d_in[3];
    const float* lin_b    = (const float*)d_in[4];
    const float* W_in     = (const float*)d_in[5];
    const float* conv1d_w = (const float*)d_in[6];
    const float* conv1d_b = (const float*)d_in[7];
    const float* W_x      = (const float*)d_in[8];
    const float* W_dt     = (const float*)d_in[9];
    const float* b_dt     = (const float*)d_in[10];
    const float* A_log    = (const float*)d_in[11];
    const float* Dp       = (const float*)d_in[12];
    const float* W_out    = (const float*)d_in[13];
    const float* We       = (const float*)d_in[14];
    const float* be       = (const float*)d_in[15];
    const float* Wa       = (const float*)d_in[16];
    const float* ba       = (const float*)d_in[17];
    const float* Wq       = (const float*)d_in[18];
    const float* bq       = (const float*)d_in[19];
    float* out = (float*)d_out;

    float* ws = (float*)d_ws;
    float* zg     = ws;                          // 512*256 each
    float* xs     = zg    + 512 * 256;
    float* delta  = xs    + 512 * 256;
    float* Bm     = delta + 512 * 256;
    float* Cm     = Bm    + 512 * 256;
    float* xmg    = Cm    + 512 * 256;
    float* ypart  = xmg   + 512 * 256;           // 4 * 512*256
    int*   flags  = (int*)(ypart + 4 * 512 * 256);
    int*   initflag = flags;                     // [0]
    int*   rowdone  = flags + 16;                // own cache line
    int*   scandone = flags + 32;                // own cache line
    int*   xmflag   = flags + 64;                // 128 flags

    mega<<<NBLK, 256, 0, stream>>>(
        x, conv_w, conv_b, lin_w, lin_b, W_in,
        conv1d_w, conv1d_b, W_x, W_dt, b_dt, A_log, Dp, W_out,
        We, be, Wa, ba, Wq, bq, out,
        zg, xs, delta, Bm, Cm, xmg, ypart,
        initflag, rowdone, scandone, xmflag);
}